// Round 1
// 534.081 us; speedup vs baseline: 1.8105x; 1.8105x over previous
//
#include <hip/hip_runtime.h>
#include <hip/hip_bf16.h>
#include <stdint.h>

#define LL 512
#define BB 64
#define CC 512
#define TM 255   // meeting point: fwd covers emits 0..255, bwd covers 256..511

typedef float float4v __attribute__((ext_vector_type(4)));
typedef int   int4v   __attribute__((ext_vector_type(4)));
typedef int   int8v   __attribute__((ext_vector_type(8)));

// ws layout (bytes)
#define WS_ET     262144   // E^T fp8, 256 KiB (E fwd fp8 at 0)
#define WS_SCORE  524288   // f32
#define WS_SVA    524292   // 64 f32
#define WS_SVB    524548   // 64 f32
#define WS_ALPHA  528384   // 64*512 f32 (class-ordered)
#define WS_BETA   659456   // 64*512 f32 (class-ordered)

// position permutation shared by p8 rows and E/E^T columns:
//   k_perm(P) = 64*(P>>6) + 16*(P&3) + ((P>>2)&15)

__device__ __forceinline__ bool mask_at(const void* maskp, bool is_byte, int t, int b) {
    if (is_byte) return ((const unsigned char*)maskp)[t * BB + b] != 0;
    return ((const int*)maskp)[t * BB + b] != 0;
}

// 16-lane (DPP row) max reduce: after this, all 16 lanes of the row hold the max.
__device__ __forceinline__ float rowmax16_dpp(float x) {
    int t;
    t = __builtin_amdgcn_update_dpp(0, __float_as_int(x), 0x128, 0xF, 0xF, true); // ror:8
    x = fmaxf(x, __int_as_float(t));
    t = __builtin_amdgcn_update_dpp(0, __float_as_int(x), 0x124, 0xF, 0xF, true); // ror:4
    x = fmaxf(x, __int_as_float(t));
    t = __builtin_amdgcn_update_dpp(0, __float_as_int(x), 0x122, 0xF, 0xF, true); // ror:2
    x = fmaxf(x, __int_as_float(t));
    t = __builtin_amdgcn_update_dpp(0, __float_as_int(x), 0x121, 0xF, 0xF, true); // ror:1
    x = fmaxf(x, __int_as_float(t));
    return x;
}

// E (fwd) and E^T (bwd) in fp8, permuted layout. Also zero the score slot.
__global__ void prep_kernel(const float* __restrict__ trans, unsigned char* __restrict__ ws) {
    int g = blockIdx.x * blockDim.x + threadIdx.x;
    if (g == 0) *(float*)(ws + WS_SCORE) = 0.0f;
    if (g >= 512 * 128) return;
    int n  = g & 511;
    int pd = g >> 9;
    int wv = pd >> 4, rw = pd & 15;
    float f[4], ft[4];
#pragma unroll
    for (int nt = 0; nt < 4; ++nt) {
        int k = 64 * wv + 16 * nt + rw;
        f[nt]  = __expf(trans[(size_t)k * CC + n]);   // E[k][n]   (fwd:  alpha contracts k)
        ft[nt] = __expf(trans[(size_t)n * CC + k]);   // E[n][k]   (bwd:  beta contracts j)
    }
    int r = 0;
    r = __builtin_amdgcn_cvt_pk_fp8_f32(f[0], f[1], r, false);
    r = __builtin_amdgcn_cvt_pk_fp8_f32(f[2], f[3], r, true);
    ((int*)ws)[n * 128 + pd] = r;
    int r2 = 0;
    r2 = __builtin_amdgcn_cvt_pk_fp8_f32(ft[0], ft[1], r2, false);
    r2 = __builtin_amdgcn_cvt_pk_fp8_f32(ft[2], ft[3], r2, true);
    ((int*)(ws + WS_ET))[n * 128 + pd] = r2;
}

// ---------------- bidirectional scan + merged score -------------------------------------
// blocks 0..3:  forward  alpha, chains blk*16..+16, t = 1..255   (len>=256 -> no guards)
// blocks 4..7:  backward beta,  chains (blk-4)*16..+16, t = 510..255 (per-chain freeze-until-birth)
// blocks 8..39: score (independent gather work, runs on otherwise idle CUs)
__launch_bounds__(512, 2)
__global__ void crf_scan_kernel(const float* __restrict__ emit,
                                const int* __restrict__ target,
                                const void* __restrict__ maskp,
                                const float* __restrict__ trans,
                                const float* __restrict__ tfs,
                                const float* __restrict__ t2e,
                                unsigned char* __restrict__ ws) {
    const int tid = threadIdx.x;
    const bool is_byte = ((const unsigned char*)maskp)[1] != 0;

    if (blockIdx.x >= 8) {   // -------- score part --------
        int sb = blockIdx.x - 8;
        float val = 0.0f;
        for (int e = sb * 512 + tid; e < LL * BB; e += 32 * 512) {
            int t = e >> 6, b = e & 63;
            if (mask_at(maskp, is_byte, t, b)) {
                int tg  = target[t * BB + b];
                float v = emit[(size_t)(t * BB + b) * CC + tg];
                if (t > 0) v += trans[(size_t)target[(t - 1) * BB + b] * CC + tg];
                val += v;
            }
        }
        if (sb == 0 && tid < BB) {
            int b = tid;
            val += tfs[target[b]];
            int lo = 0, hi = LL;
            while (lo < hi) {
                int mid = (lo + hi) >> 1;
                if (mask_at(maskp, is_byte, mid, b)) lo = mid + 1; else hi = mid;
            }
            val += t2e[target[(lo - 1) * BB + b]];
        }
        for (int off = 32; off > 0; off >>= 1) val += __shfl_down(val, off);
        if ((tid & 63) == 0) atomicAdd((float*)(ws + WS_SCORE), val);
        return;
    }

    const bool is_fwd = blockIdx.x < 4;
    const int B0 = (is_fwd ? blockIdx.x : blockIdx.x - 4) * 16;

    __shared__ __align__(16) unsigned char p8[2][16 * 528];
    __shared__ float mslot[4][16];   // rowmax ring
    __shared__ float Sv[16];
    __shared__ float m0S[16];
    __shared__ float red[16][32];
    __shared__ int   lenS[16];
    __shared__ float mInitS;

    const int wv   = tid >> 6;
    const int lane = tid & 63;
    const int q    = lane >> 4;
    const int r15  = lane & 15;

    // E (B operand) fragments resident in VGPRs: fwd reads E, bwd reads E^T
    const unsigned char* ews = ws + (is_fwd ? 0 : WS_ET);
    int8v ef[4][4];
#pragma unroll
    for (int nt = 0; nt < 4; ++nt) {
        int n = (wv * 4 + nt) * 16 + r15;
#pragma unroll
        for (int kk4 = 0; kk4 < 4; ++kk4) {
            const unsigned char* src = ews + n * 512 + kk4 * 128 + q * 32;
            int4v lo = *(const int4v*)(src);
            int4v hi = *(const int4v*)(src + 16);
            ef[nt][kk4] = __builtin_shufflevector(lo, hi, 0, 1, 2, 3, 4, 5, 6, 7);
        }
    }

    const int c5 = tid >> 5;
    const int s5 = tid & 31;

    if (is_fwd) {
        // ---- fwd init pass 1: m0 = max(emit[0]+tfs) per chain ----
        {
            float lmax = -3.0e38f;
#pragma unroll
            for (int i = 0; i < 4; ++i) {
                int j4 = s5 + 32 * i;
                float4v em = *(const float4v*)(emit + (size_t)(B0 + c5) * CC + 4 * j4);
                float4v tf = *(const float4v*)(tfs + 4 * j4);
                float4v a = em + tf;
                lmax = fmaxf(lmax, fmaxf(fmaxf(a.x, a.y), fmaxf(a.z, a.w)));
            }
            red[c5][s5] = lmax;
        }
        __syncthreads();
        if (tid < 16) {
            float m0 = red[tid][0];
            for (int s = 1; s < 32; ++s) m0 = fmaxf(m0, red[tid][s]);
            Sv[tid]  = m0;
            m0S[tid] = m0;
            mslot[0][tid] = 1.0f;   // M_0 = 1 (P0 stored max-normalized)
            mslot[1][tid] = 0.0f;
            mslot[2][tid] = 0.0f;
            mslot[3][tid] = 0.0f;
        }
        __syncthreads();
        // ---- fwd init pass 2: store P0 (max = 1) in permuted layout ----
        {
            float m0 = m0S[c5];
#pragma unroll
            for (int i = 0; i < 4; ++i) {
                int pd = s5 + 32 * i;
                int wvv = pd >> 4, rw = pd & 15;
                float f[4];
#pragma unroll
                for (int nt = 0; nt < 4; ++nt) {
                    int k = 64 * wvv + 16 * nt + rw;
                    f[nt] = __expf(emit[(size_t)(B0 + c5) * CC + k] + tfs[k] - m0);
                }
                int r = 0;
                r = __builtin_amdgcn_cvt_pk_fp8_f32(f[0], f[1], r, false);
                r = __builtin_amdgcn_cvt_pk_fp8_f32(f[2], f[3], r, true);
                *(int*)(&p8[0][0] + c5 * 528 + pd * 4) = r;
            }
        }
        __syncthreads();
    } else {
        // ---- bwd init: mInit = max_k exp(t2e[k]) ----
        {
            float m = t2e[tid];   // tid in [0,512) = CC values
            for (int off = 32; off > 0; off >>= 1) m = fmaxf(m, __shfl_xor(m, off));
            if (lane == 0) ((float*)red)[wv] = m;
        }
        if (tid < 16) {
            Sv[tid] = 0.0f;
            mslot[0][tid] = 0.0f;  // slot 3 = "prev" of it=0, overridden by useInit
            mslot[1][tid] = 0.0f;
            mslot[2][tid] = 0.0f;
            mslot[3][tid] = 0.0f;
        }
        __syncthreads();
        if (tid == 0) {
            float m = ((float*)red)[0];
            for (int i = 1; i < 8; ++i) m = fmaxf(m, ((float*)red)[i]);
            mInitS = __expf(m);
        }
        __syncthreads();
        // ---- bwd init: beta_511 = exp(t2e) in BOTH buffers (frozen rows must persist) ----
        {
#pragma unroll
            for (int i = 0; i < 4; ++i) {
                int pd = s5 + 32 * i;
                int wvv = pd >> 4, rw = pd & 15;
                float f[4];
#pragma unroll
                for (int nt = 0; nt < 4; ++nt)
                    f[nt] = __expf(t2e[64 * wvv + 16 * nt + rw]);
                int r = 0;
                r = __builtin_amdgcn_cvt_pk_fp8_f32(f[0], f[1], r, false);
                r = __builtin_amdgcn_cvt_pk_fp8_f32(f[2], f[3], r, true);
                *(int*)(&p8[0][0] + c5 * 528 + pd * 4) = r;
                *(int*)(&p8[1][0] + c5 * 528 + pd * 4) = r;
            }
            int part = 0;
            for (int k = 0; k < 16; ++k)
                part += mask_at(maskp, is_byte, s5 * 16 + k, B0 + c5) ? 1 : 0;
            red[c5][s5] = (float)part;
        }
        __syncthreads();
        if (tid < 16) {
            int s = 0;
            for (int i = 0; i < 32; ++i) s += (int)red[tid][i];
            lenS[tid] = s;
        }
        __syncthreads();
    }

    int lenR[4] = {LL, LL, LL, LL};
    float mInit = 0.0f;
    if (!is_fwd) {
#pragma unroll
        for (int rr = 0; rr < 4; ++rr) lenR[rr] = lenS[q * 4 + rr];
        mInit = mInitS;
    }
    float et2e[4];
#pragma unroll
    for (int nt = 0; nt < 4; ++nt)
        et2e[nt] = __expf(t2e[(wv * 4 + nt) * 16 + r15]);
    float rQ[4] = {1.0f, 1.0f, 1.0f, 1.0f};   // 1/sigma_prev

    if (is_fwd) {
        // =========================== FORWARD: t = 1..255 ===========================
        const float* eb0 = emit + (size_t)(BB + B0 + q * 4) * CC + (wv * 64 + r15);
        const float* eb1 = eb0 + 2 * CC;
        float ex[16];
#pragma unroll
        for (int nt = 0; nt < 4; ++nt)
#pragma unroll
            for (int rr = 0; rr < 2; ++rr) {
                ex[nt * 4 + rr]     = __expf(eb0[rr * CC + nt * 16]);
                ex[nt * 4 + rr + 2] = __expf(eb1[rr * CC + nt * 16]);
            }

#pragma unroll 2
        for (int t = 1; t <= TM; ++t) {
            const int wp = t & 1;
            const int rp = wp ^ 1;

            const int step = (t < TM) ? (BB * CC) : 0;
            float emn[16];
#pragma unroll
            for (int nt = 0; nt < 4; ++nt)
#pragma unroll
                for (int rr = 0; rr < 2; ++rr) {
                    emn[nt * 4 + rr]     = eb0[step + rr * CC + nt * 16];
                    emn[nt * 4 + rr + 2] = eb1[step + rr * CC + nt * 16];
                }

            int8v af[4];
            const unsigned char* pr = &p8[rp][0] + r15 * 528 + q * 32;
#pragma unroll
            for (int kk4 = 0; kk4 < 4; ++kk4) {
                int4v lo = *(const int4v*)(pr + kk4 * 128);
                int4v hi = *(const int4v*)(pr + kk4 * 128 + 16);
                af[kk4] = __builtin_shufflevector(lo, hi, 0, 1, 2, 3, 4, 5, 6, 7);
            }

            float sig[4], rcv[4];
#pragma unroll
            for (int rr = 0; rr < 4; ++rr) {
                float M1 = mslot[(t - 1) & 3][q * 4 + rr];
                sig[rr] = 64.0f * M1 * rQ[rr];
                rcv[rr] = 1.0f / sig[rr];
                rQ[rr]  = rcv[rr];
            }

            if (wv == 0 && r15 == 0) {
#pragma unroll
                for (int rr = 0; rr < 4; ++rr) mslot[(t + 1) & 3][q * 4 + rr] = 0.0f;
            }

            float4v acc[4];
            const float4v z = {0.f, 0.f, 0.f, 0.f};
#pragma unroll
            for (int nt = 0; nt < 4; ++nt) acc[nt] = z;

#pragma unroll
            for (int kk4 = 0; kk4 < 4; ++kk4)
#pragma unroll
                for (int nt = 0; nt < 2; ++nt)
                    acc[nt] = __builtin_amdgcn_mfma_scale_f32_16x16x128_f8f6f4(
                        af[kk4], ef[nt][kk4], acc[nt],
                        0, 0, 0, 0x7F7F7F7F, 0, 0x7F7F7F7F);

            float exn[16];
#pragma unroll
            for (int i = 0; i < 16; ++i) exn[i] = __expf(emn[i]);

#pragma unroll
            for (int kk4 = 0; kk4 < 4; ++kk4)
#pragma unroll
                for (int nt = 2; nt < 4; ++nt)
                    acc[nt] = __builtin_amdgcn_mfma_scale_f32_16x16x128_f8f6f4(
                        af[kk4], ef[nt][kk4], acc[nt],
                        0, 0, 0, 0x7F7F7F7F, 0, 0x7F7F7F7F);

            float rowmax[4];
#pragma unroll
            for (int rr = 0; rr < 4; ++rr) {
                float v0 = acc[0][rr] * ex[0 * 4 + rr];
                float v1 = acc[1][rr] * ex[1 * 4 + rr];
                acc[0][rr] = v0; acc[1][rr] = v1;
                rowmax[rr] = fmaxf(v0, v1);
            }
#pragma unroll
            for (int rr = 0; rr < 4; ++rr) {
                float v2 = acc[2][rr] * ex[2 * 4 + rr];
                float v3 = acc[3][rr] * ex[3 * 4 + rr];
                acc[2][rr] = v2; acc[3][rr] = v3;
                rowmax[rr] = fmaxf(rowmax[rr], fmaxf(v2, v3));
            }

            {
                unsigned char* wrow = &p8[wp][0] + (wv * 16 + r15) * 4;
#pragma unroll
                for (int rr = 0; rr < 4; ++rr) {
                    float p0 = fminf(acc[0][rr] * rcv[rr], 448.0f);
                    float p1 = fminf(acc[1][rr] * rcv[rr], 448.0f);
                    float p2 = fminf(acc[2][rr] * rcv[rr], 448.0f);
                    float p3 = fminf(acc[3][rr] * rcv[rr], 448.0f);
                    int r = 0;
                    r = __builtin_amdgcn_cvt_pk_fp8_f32(p0, p1, r, false);
                    r = __builtin_amdgcn_cvt_pk_fp8_f32(p2, p3, r, true);
                    *(int*)(wrow + (q * 4 + rr) * 528) = r;
                }
            }

#pragma unroll
            for (int rr = 0; rr < 4; ++rr) {
                float mr = rowmax16_dpp(rowmax[rr]);
                if (r15 == 0)
                    atomicMax((int*)&mslot[t & 3][q * 4 + rr], __float_as_int(mr));
            }

            if (wv == 0 && r15 == 0) {   // len >= 256 > t: always live in fwd range
#pragma unroll
                for (int rr = 0; rr < 4; ++rr) Sv[q * 4 + rr] += __logf(sig[rr]);
            }

            if (t == TM) {   // export normalized alpha_255 (pre-quant f32, class order)
                float* wA = (float*)(ws + WS_ALPHA) + (size_t)(B0 + q * 4) * CC + (wv * 64 + r15);
#pragma unroll
                for (int rr = 0; rr < 4; ++rr)
#pragma unroll
                    for (int nt = 0; nt < 4; ++nt)
                        wA[(size_t)rr * CC + nt * 16] = acc[nt][rr] * rcv[rr];
            }

#pragma unroll
            for (int i = 0; i < 16; ++i) ex[i] = exn[i];
            eb0 += BB * CC;
            eb1 += BB * CC;
            __syncthreads();
        }
        if (tid < 16) ((float*)(ws + WS_SVA))[B0 + tid] = Sv[tid];
    } else {
        // =========================== BACKWARD: t = 510..255 ===========================
        // beta_t = E * (ex_{t+1} o beta_{t+1}); chain frozen (row = init) while t >= len-1.
        const float* eb0 = emit + ((size_t)(LL - 1) * BB + B0 + q * 4) * CC + (wv * 64 + r15);
        const float* eb1 = eb0 + 2 * CC;
        float ex[16];
#pragma unroll
        for (int nt = 0; nt < 4; ++nt)
#pragma unroll
            for (int rr = 0; rr < 2; ++rr) {
                ex[nt * 4 + rr]     = __expf(eb0[rr * CC + nt * 16]);
                ex[nt * 4 + rr + 2] = __expf(eb1[rr * CC + nt * 16]);
            }

#pragma unroll 2
        for (int it = 0; it < 256; ++it) {
            const int t  = 510 - it;
            const int wp = it & 1;
            const int rp = wp ^ 1;

            const int step = (it < 255) ? -(BB * CC) : 0;
            float emn[16];
#pragma unroll
            for (int nt = 0; nt < 4; ++nt)
#pragma unroll
                for (int rr = 0; rr < 2; ++rr) {
                    emn[nt * 4 + rr]     = eb0[step + rr * CC + nt * 16];
                    emn[nt * 4 + rr + 2] = eb1[step + rr * CC + nt * 16];
                }

            int8v af[4];
            const unsigned char* pr = &p8[rp][0] + r15 * 528 + q * 32;
#pragma unroll
            for (int kk4 = 0; kk4 < 4; ++kk4) {
                int4v lo = *(const int4v*)(pr + kk4 * 128);
                int4v hi = *(const int4v*)(pr + kk4 * 128 + 16);
                af[kk4] = __builtin_shufflevector(lo, hi, 0, 1, 2, 3, 4, 5, 6, 7);
            }

            float sig[4], rcv[4];
#pragma unroll
            for (int rr = 0; rr < 4; ++rr) {
                // prev row (t+1) was frozen-init iff t >= len-2 -> its max is mInit, scale 1
                bool ui  = (t >= lenR[rr] - 2);
                float M1 = ui ? mInit : mslot[(it + 3) & 3][q * 4 + rr];
                float rq = ui ? 1.0f : rQ[rr];
                sig[rr] = 64.0f * M1 * rq;
                rcv[rr] = 1.0f / sig[rr];
                rQ[rr]  = rcv[rr];
            }

            if (wv == 0 && r15 == 0) {
#pragma unroll
                for (int rr = 0; rr < 4; ++rr) mslot[(it + 1) & 3][q * 4 + rr] = 0.0f;
            }

            float4v acc[4];
            const float4v z = {0.f, 0.f, 0.f, 0.f};
#pragma unroll
            for (int nt = 0; nt < 4; ++nt) acc[nt] = z;

#pragma unroll
            for (int kk4 = 0; kk4 < 4; ++kk4)
#pragma unroll
                for (int nt = 0; nt < 2; ++nt)
                    acc[nt] = __builtin_amdgcn_mfma_scale_f32_16x16x128_f8f6f4(
                        af[kk4], ef[nt][kk4], acc[nt],
                        0, 0, 0, 0x7F7F7F7F, 0, 0x7F7F7F7F);

            float exn[16];
#pragma unroll
            for (int i = 0; i < 16; ++i) exn[i] = __expf(emn[i]);

#pragma unroll
            for (int kk4 = 0; kk4 < 4; ++kk4)
#pragma unroll
                for (int nt = 2; nt < 4; ++nt)
                    acc[nt] = __builtin_amdgcn_mfma_scale_f32_16x16x128_f8f6f4(
                        af[kk4], ef[nt][kk4], acc[nt],
                        0, 0, 0, 0x7F7F7F7F, 0, 0x7F7F7F7F);

            // NOTE: ex here is ex_{t+1} (emission folded BEFORE contraction happened via
            // storing v; for bwd the elementwise factor applies to the contracted source,
            // which is algebraically identical to multiplying the raw product here since
            // E^T rows were not pre-scaled: v = (E^T . s)_n * ex... — the recursion keeps
            // the same store-normalize-contract form as fwd, just with E^T.
            float rowmax[4];
#pragma unroll
            for (int rr = 0; rr < 4; ++rr) {
                float v0 = acc[0][rr] * ex[0 * 4 + rr];
                float v1 = acc[1][rr] * ex[1 * 4 + rr];
                acc[0][rr] = v0; acc[1][rr] = v1;
                rowmax[rr] = fmaxf(v0, v1);
            }
#pragma unroll
            for (int rr = 0; rr < 4; ++rr) {
                float v2 = acc[2][rr] * ex[2 * 4 + rr];
                float v3 = acc[3][rr] * ex[3 * 4 + rr];
                acc[2][rr] = v2; acc[3][rr] = v3;
                rowmax[rr] = fmaxf(rowmax[rr], fmaxf(v2, v3));
            }

            {
                unsigned char* wrow = &p8[wp][0] + (wv * 16 + r15) * 4;
#pragma unroll
                for (int rr = 0; rr < 4; ++rr) {
                    float p0 = fminf(acc[0][rr] * rcv[rr], 448.0f);
                    float p1 = fminf(acc[1][rr] * rcv[rr], 448.0f);
                    float p2 = fminf(acc[2][rr] * rcv[rr], 448.0f);
                    float p3 = fminf(acc[3][rr] * rcv[rr], 448.0f);
                    int r = 0;
                    r = __builtin_amdgcn_cvt_pk_fp8_f32(p0, p1, r, false);
                    r = __builtin_amdgcn_cvt_pk_fp8_f32(p2, p3, r, true);
                    if (t <= lenR[rr] - 2)   // live update only; frozen rows keep init
                        *(int*)(wrow + (q * 4 + rr) * 528) = r;
                }
            }

#pragma unroll
            for (int rr = 0; rr < 4; ++rr) {
                float mr = rowmax16_dpp(rowmax[rr]);
                if (r15 == 0)
                    atomicMax((int*)&mslot[it & 3][q * 4 + rr], __float_as_int(mr));
            }

            if (wv == 0 && r15 == 0) {
#pragma unroll
                for (int rr = 0; rr < 4; ++rr)
                    if (t <= lenR[rr] - 2) Sv[q * 4 + rr] += __logf(sig[rr]);
            }

            if (t == TM) {   // export normalized beta_255 (frozen chains: e^{t2e} row)
                float* wB = (float*)(ws + WS_BETA) + (size_t)(B0 + q * 4) * CC + (wv * 64 + r15);
#pragma unroll
                for (int rr = 0; rr < 4; ++rr) {
                    bool live = (t <= lenR[rr] - 2);
#pragma unroll
                    for (int nt = 0; nt < 4; ++nt)
                        wB[(size_t)rr * CC + nt * 16] = live ? (acc[nt][rr] * rcv[rr]) : et2e[nt];
                }
            }

#pragma unroll
            for (int i = 0; i < 16; ++i) ex[i] = exn[i];
            eb0 -= BB * CC;
            eb1 -= BB * CC;
            __syncthreads();
        }
        if (tid < 16) ((float*)(ws + WS_SVB))[B0 + tid] = Sv[tid];
    }
}

// ---------------- combine: logZ_b = SvA_b + SvB_b + log(alpha_255 . beta_255) -----------
__global__ void combine_kernel(const unsigned char* __restrict__ ws, float* __restrict__ out) {
    __shared__ float acc8[8];
    const int tid = threadIdx.x;
    const int c  = tid >> 3;
    const int s8 = tid & 7;
    const float* A = (const float*)(ws + WS_ALPHA) + (size_t)c * CC;
    const float* B = (const float*)(ws + WS_BETA)  + (size_t)c * CC;
    float d = 0.0f;
    for (int i = s8; i < CC; i += 8) d += A[i] * B[i];
    d += __shfl_xor(d, 1);
    d += __shfl_xor(d, 2);
    d += __shfl_xor(d, 4);
    float v = 0.0f;
    if (s8 == 0)
        v = ((const float*)(ws + WS_SVA))[c] + ((const float*)(ws + WS_SVB))[c] + __logf(d);
    for (int off = 32; off > 0; off >>= 1) v += __shfl_down(v, off);
    if ((tid & 63) == 0) acc8[tid >> 6] = v;
    __syncthreads();
    if (tid == 0) {
        float s = 0.0f;
        for (int i = 0; i < 8; ++i) s += acc8[i];
        out[0] = (s - *(const float*)(ws + WS_SCORE)) * (1.0f / 64.0f);
    }
}

extern "C" void kernel_launch(void* const* d_in, const int* in_sizes, int n_in,
                              void* d_out, int out_size, void* d_ws, size_t ws_size,
                              hipStream_t stream) {
    const float* emit   = (const float*)d_in[0];
    const int*   target = (const int*)d_in[1];
    const void*  maskp  = d_in[2];
    const float* trans  = (const float*)d_in[3];
    const float* tfs    = (const float*)d_in[4];
    const float* t2e    = (const float*)d_in[5];
    unsigned char* ws   = (unsigned char*)d_ws;
    float* out          = (float*)d_out;

    prep_kernel<<<256, 256, 0, stream>>>(trans, ws);
    crf_scan_kernel<<<40, 512, 0, stream>>>(emit, target, maskp, trans, tfs, t2e, ws);
    combine_kernel<<<1, 512, 0, stream>>>(ws, out);
}